// Round 2
// baseline (905.764 us; speedup 1.0000x reference)
//
#include <hip/hip_runtime.h>
#include <math.h>

#define H      2048
#define HV     512          // H/4
#define E      64
#define MTOK   8            // tokens per wave
#define T_TOK  32768        // 4*8192
#define GATES_OFF   0
#define IDX_OFF     65536
#define LOSS_OFF    131072

// ---------------- W transpose: W[e][h] -> Wt[(h/4)][e][h%4] (float4 per (h4,e)) ---
__global__ void transpose_w_kernel(const float* __restrict__ W, float* __restrict__ Wt) {
    int id = blockIdx.x * 256 + threadIdx.x;       // 131072 total
    int e = id >> 11;                               // / 2048
    int h = id & 2047;
    Wt[(h >> 2) * 256 + (e << 2) + (h & 3)] = W[id];
}

// ---------------- main gating kernel ----------------
__global__ __launch_bounds__(256) void gate_main_kernel(
        const float* __restrict__ x,         // (T, H)
        const float4* __restrict__ wt,       // [HV][E] float4
        float* __restrict__ out,
        float* __restrict__ accum)           // [0:64) sum probs, [64:128) counts
{
    const int lane = threadIdx.x & 63;
    const int wave = threadIdx.x >> 6;
    const int gwave = blockIdx.x * 4 + wave;
    const int tokBase = __builtin_amdgcn_readfirstlane(gwave * MTOK);

    // Launder the (runtime-uniform) token base through a shuffle so divergence
    // analysis marks it divergent -> X loads stay on the VECTOR memory pipe
    // (vmcnt, deep pipelining) instead of being scalarized to s_load
    // (lgkmcnt(0) full-drain per iteration = exposed HBM latency, R1's 448us).
    const int tokBaseV = __shfl(tokBase, 0);
    const float4* xq = (const float4*)x + (size_t)tokBaseV * HV;

    float acc[MTOK];
#pragma unroll
    for (int m = 0; m < MTOK; ++m) acc[m] = 0.f;

    // ---- 2-deep software-pipelined K loop ----
    float4 xb0[MTOK], xb1[MTOK];
    float4 wb0, wb1;

    wb0 = wt[0 * E + lane];
    wb1 = wt[1 * E + lane];
#pragma unroll
    for (int m = 0; m < MTOK; ++m) {
        xb0[m] = xq[m * HV + 0];
        xb1[m] = xq[m * HV + 1];
    }

    for (int i = 0; i < HV; i += 2) {
        // snapshot current buffers (SSA copies, free)
        float4 w0 = wb0, w1 = wb1;
        float4 x0[MTOK], x1[MTOK];
#pragma unroll
        for (int m = 0; m < MTOK; ++m) { x0[m] = xb0[m]; x1[m] = xb1[m]; }

        // issue next iteration's 18 loads BEFORE the FMAs consume current ones
        if (i + 2 < HV) {
            wb0 = wt[(i + 2) * E + lane];
            wb1 = wt[(i + 3) * E + lane];
#pragma unroll
            for (int m = 0; m < MTOK; ++m) {
                xb0[m] = xq[m * HV + i + 2];
                xb1[m] = xq[m * HV + i + 3];
            }
        }

#pragma unroll
        for (int m = 0; m < MTOK; ++m) {
            float a = acc[m];
            a = fmaf(x0[m].x, w0.x, a);
            a = fmaf(x0[m].y, w0.y, a);
            a = fmaf(x0[m].z, w0.z, a);
            a = fmaf(x0[m].w, w0.w, a);
            a = fmaf(x1[m].x, w1.x, a);
            a = fmaf(x1[m].y, w1.y, a);
            a = fmaf(x1[m].z, w1.z, a);
            a = fmaf(x1[m].w, w1.w, a);
            acc[m] = a;
        }
    }

    float sumP = 0.f, cntP = 0.f;

#pragma unroll
    for (int m = 0; m < MTOK; ++m) {
        float v = acc[m];                    // logit(token, expert=lane)

        // full softmax over 64 experts (for aux loss)
        float vmax = v;
#pragma unroll
        for (int d = 32; d > 0; d >>= 1) vmax = fmaxf(vmax, __shfl_xor(vmax, d, 64));
        float ex = expf(v - vmax);
        float s = ex;
#pragma unroll
        for (int d = 32; d > 0; d >>= 1) s += __shfl_xor(s, d, 64);
        float p = ex / s;
        sumP += p;
        cntP += (p > 0.f) ? 1.f : 0.f;

        // top-1 (tie -> lower index, matching lax.top_k)
        float v1 = v; int i1 = lane;
#pragma unroll
        for (int d = 32; d > 0; d >>= 1) {
            float ov = __shfl_xor(v1, d, 64);
            int   oi = __shfl_xor(i1, d, 64);
            if (ov > v1 || (ov == v1 && oi < i1)) { v1 = ov; i1 = oi; }
        }
        // top-2: mask out i1
        float v2 = (lane == i1) ? -INFINITY : v; int i2 = lane;
#pragma unroll
        for (int d = 32; d > 0; d >>= 1) {
            float ov = __shfl_xor(v2, d, 64);
            int   oi = __shfl_xor(i2, d, 64);
            if (ov > v2 || (ov == v2 && oi < i2)) { v2 = ov; i2 = oi; }
        }

        if (lane == 0) {
            int token = tokBase + m;
            float t  = expf(v2 - v1);        // softmax([v1,v2]) with max subtracted
            float d  = 1.f / (1.f + t);
            out[GATES_OFF + 2 * token]     = d;
            out[GATES_OFF + 2 * token + 1] = t * d;
            out[IDX_OFF   + 2 * token]     = (float)i1;
            out[IDX_OFF   + 2 * token + 1] = (float)i2;
        }
    }

    // block-level reduction of per-expert prob sums / counts, one atomic instr per block
    __shared__ float redP[4][64];
    __shared__ float redC[4][64];
    redP[wave][lane] = sumP;
    redC[wave][lane] = cntP;
    __syncthreads();
    if (wave == 0) {
        float sp = redP[0][lane] + redP[1][lane] + redP[2][lane] + redP[3][lane];
        float sc = redC[0][lane] + redC[1][lane] + redC[2][lane] + redC[3][lane];
        atomicAdd(&accum[lane], sp);
        atomicAdd(&accum[E + lane], sc);
    }
}

// ---------------- final loss kernel ----------------
__global__ void gate_final_kernel(const float* __restrict__ accum, float* __restrict__ out) {
    int lane = threadIdx.x;                  // 64 threads
    const float invT = 1.f / (float)T_TOK;
    float mean_p   = accum[lane] * invT;
    float routing  = accum[E + lane] * invT;
    float term = mean_p * routing;
#pragma unroll
    for (int d = 32; d > 0; d >>= 1) term += __shfl_xor(term, d, 64);
    if (lane == 0) out[LOSS_OFF] = 64.f * term;
}

extern "C" void kernel_launch(void* const* d_in, const int* in_sizes, int n_in,
                              void* d_out, int out_size, void* d_ws, size_t ws_size,
                              hipStream_t stream) {
    const float* x = (const float*)d_in[0];   // (4,8192,2048) fp32
    const float* W = (const float*)d_in[1];   // (64,2048) fp32
    float* out   = (float*)d_out;
    float* accum = (float*)d_ws;              // 128 floats
    float* Wt    = (float*)d_ws + 128;        // 131072 floats (16B-aligned)

    hipMemsetAsync(accum, 0, 128 * sizeof(float), stream);
    transpose_w_kernel<<<512, 256, 0, stream>>>(W, Wt);
    gate_main_kernel<<<T_TOK / (MTOK * 4), 256, 0, stream>>>(x, (const float4*)Wt, out, accum);
    gate_final_kernel<<<1, 64, 0, stream>>>(accum, out);
}

// Round 3
// 584.807 us; speedup vs baseline: 1.5488x; 1.5488x over previous
//
#include <hip/hip_runtime.h>
#include <math.h>

#define H      2048
#define E      64
#define MTOK   16           // tokens per wave
#define BTOK   64           // tokens per block (4 waves)
#define KC     64           // k-floats per chunk
#define KC4    16           // KC/4
#define NCHUNK (H / KC)     // 32
#define T_TOK  32768
#define GATES_OFF   0
#define IDX_OFF     65536
#define LOSS_OFF    131072

// ---- W transpose: W[e][h] -> Wt[h/4][e][h%4]; also zero-inits accum ----
__global__ void transpose_w_kernel(const float* __restrict__ W, float* __restrict__ Wt,
                                   float* __restrict__ accum) {
    int id = blockIdx.x * 256 + threadIdx.x;       // 131072 total
    if (blockIdx.x == 0 && threadIdx.x < 128) accum[threadIdx.x] = 0.f;
    int e = id >> 11;
    int h = id & 2047;
    Wt[(h >> 2) * 256 + (e << 2) + (h & 3)] = W[id];
}

__device__ __forceinline__ void async_copy16(const float* g, void* l) {
    __builtin_amdgcn_global_load_lds(
        (const __attribute__((address_space(1))) unsigned int*)g,
        (__attribute__((address_space(3))) unsigned int*)l,
        16, 0, 0);
}

// ---------------- main gating kernel ----------------
__global__ __launch_bounds__(256) void gate_main_kernel(
        const float* __restrict__ x,         // (T, H)
        const float4* __restrict__ wt4,      // [H/4][E] float4
        float* __restrict__ out,
        float* __restrict__ accum)           // [0:64) sum probs, [64:128) counts
{
    __shared__ float4 xtile[2][BTOK * KC4];  // 2 x 16 KB, [token][k4] per buffer
    __shared__ float  redP[4][64];
    __shared__ float  redC[4][64];

    const int tid  = threadIdx.x;
    const int lane = tid & 63;
    const int wave = tid >> 6;
    const int tokBase = blockIdx.x * BTOK;

    const float* xg = x + (size_t)tokBase * H;

    // stage chunk c into buffer b: 1024 float4s, 4 per thread, coalesced 16B/lane.
    // LDS dest = wave-uniform base + lane*16 (f = j*256 + wave*64 + lane) -- satisfies
    // the global_load_lds contiguity constraint; layout [token][k4] drops out exactly.
    auto stage = [&](int c, int b) {
#pragma unroll
        for (int j = 0; j < 4; ++j) {
            int f = tid + j * 256;           // float4 index in tile
            int token = f >> 4;
            int k4 = f & 15;
            async_copy16(xg + (size_t)token * H + c * KC + k4 * 4, &xtile[b][f]);
        }
    };

    float acc[MTOK];
#pragma unroll
    for (int m = 0; m < MTOK; ++m) acc[m] = 0.f;

    stage(0, 0);

    for (int c = 0; c < NCHUNK; ++c) {
        const int b = c & 1;
        // barrier drains this wave's outstanding global_load_lds (compiler emits
        // vmcnt(0) before s_barrier) -> buf b ready, buf b^1 free for prefetch.
        __syncthreads();
        if (c + 1 < NCHUNK) stage(c + 1, b ^ 1);   // ~900cy latency hides under 2048cy FMA

        const float4* xw = &xtile[b][wave * (MTOK * KC4)];
        const float4* wp = wt4 + (size_t)c * (KC4 * E) + lane;
#pragma unroll
        for (int k4 = 0; k4 < KC4; ++k4) {
            float4 wv = wp[k4 * E];          // coalesced 1024B/instr, L2-resident
#pragma unroll
            for (int m = 0; m < MTOK; ++m) {
                float4 xv = xw[m * KC4 + k4];    // uniform addr -> LDS broadcast
                float a = acc[m];
                a = fmaf(xv.x, wv.x, a);
                a = fmaf(xv.y, wv.y, a);
                a = fmaf(xv.z, wv.z, a);
                a = fmaf(xv.w, wv.w, a);
                acc[m] = a;
            }
        }
    }

    float sumP = 0.f, cntP = 0.f;
    const int tokW = tokBase + wave * MTOK;

#pragma unroll
    for (int m = 0; m < MTOK; ++m) {
        float v = acc[m];                    // logit(token, expert=lane)

        // full softmax over 64 experts (for aux loss)
        float vmax = v;
#pragma unroll
        for (int d = 32; d > 0; d >>= 1) vmax = fmaxf(vmax, __shfl_xor(vmax, d, 64));
        float ex = expf(v - vmax);
        float s = ex;
#pragma unroll
        for (int d = 32; d > 0; d >>= 1) s += __shfl_xor(s, d, 64);
        float p = ex / s;
        sumP += p;
        cntP += (p > 0.f) ? 1.f : 0.f;

        // top-1 (tie -> lower index, matching lax.top_k)
        float v1 = v; int i1 = lane;
#pragma unroll
        for (int d = 32; d > 0; d >>= 1) {
            float ov = __shfl_xor(v1, d, 64);
            int   oi = __shfl_xor(i1, d, 64);
            if (ov > v1 || (ov == v1 && oi < i1)) { v1 = ov; i1 = oi; }
        }
        // top-2: mask out i1
        float v2 = (lane == i1) ? -INFINITY : v; int i2 = lane;
#pragma unroll
        for (int d = 32; d > 0; d >>= 1) {
            float ov = __shfl_xor(v2, d, 64);
            int   oi = __shfl_xor(i2, d, 64);
            if (ov > v2 || (ov == v2 && oi < i2)) { v2 = ov; i2 = oi; }
        }

        if (lane == 0) {
            int token = tokW + m;
            float t  = expf(v2 - v1);        // softmax([v1,v2]) with max subtracted
            float d  = 1.f / (1.f + t);
            out[GATES_OFF + 2 * token]     = d;
            out[GATES_OFF + 2 * token + 1] = t * d;
            out[IDX_OFF   + 2 * token]     = (float)i1;
            out[IDX_OFF   + 2 * token + 1] = (float)i2;
        }
    }

    // block-level reduction of per-expert prob sums / counts, one atomic per block
    redP[wave][lane] = sumP;
    redC[wave][lane] = cntP;
    __syncthreads();
    if (wave == 0) {
        float sp = redP[0][lane] + redP[1][lane] + redP[2][lane] + redP[3][lane];
        float sc = redC[0][lane] + redC[1][lane] + redC[2][lane] + redC[3][lane];
        atomicAdd(&accum[lane], sp);
        atomicAdd(&accum[E + lane], sc);
    }
}

// ---------------- final loss kernel ----------------
__global__ void gate_final_kernel(const float* __restrict__ accum, float* __restrict__ out) {
    int lane = threadIdx.x;                  // 64 threads
    const float invT = 1.f / (float)T_TOK;
    float mean_p   = accum[lane] * invT;
    float routing  = accum[E + lane] * invT;
    float term = mean_p * routing;
#pragma unroll
    for (int d = 32; d > 0; d >>= 1) term += __shfl_xor(term, d, 64);
    if (lane == 0) out[LOSS_OFF] = 64.f * term;
}

extern "C" void kernel_launch(void* const* d_in, const int* in_sizes, int n_in,
                              void* d_out, int out_size, void* d_ws, size_t ws_size,
                              hipStream_t stream) {
    const float* x = (const float*)d_in[0];   // (4,8192,2048) fp32
    const float* W = (const float*)d_in[1];   // (64,2048) fp32
    float* out   = (float*)d_out;
    float* accum = (float*)d_ws;              // 128 floats
    float* Wt    = (float*)d_ws + 128;        // 131072 floats (16B-aligned)

    transpose_w_kernel<<<512, 256, 0, stream>>>(W, Wt, accum);
    gate_main_kernel<<<T_TOK / BTOK, 256, 0, stream>>>(x, (const float4*)Wt, out, accum);
    gate_final_kernel<<<1, 64, 0, stream>>>(accum, out);
}